// Round 13
// baseline (22.493 us; speedup 1.0000x reference)
//
#include <hip/hip_runtime.h>
#include <math.h>

#define NP 196
#define NCLS 10

typedef _Float16 h2 __attribute__((ext_vector_type(2)));

#if defined(__has_builtin)
#  if __has_builtin(__builtin_amdgcn_fdot2)
#    define HAVE_FDOT2 1
#  endif
#endif
#ifndef HAVE_FDOT2
#  define HAVE_FDOT2 0
#endif

__device__ __forceinline__ float dot4_h(h2 qa, h2 qb, h2 ea, h2 eb) {
#if HAVE_FDOT2
    return __builtin_amdgcn_fdot2(qb, eb,
               __builtin_amdgcn_fdot2(qa, ea, 0.0f, false), false);
#else
    return (float)qa.x * (float)ea.x + (float)qa.y * (float)ea.y
         + (float)qb.x * (float)eb.x + (float)qb.y * (float)eb.y;
#endif
}

__device__ __forceinline__ h2 f_to_h2(float f) { return __builtin_bit_cast(h2, f); }
__device__ __forceinline__ float h2_to_f(h2 h) { return __builtin_bit_cast(float, h); }

// Block = 256 threads (4 waves), one image per block, grid = B = 1024.
// r12 (f16 pair body) + SINGLE-b128 broadcast: per-m LDS payload packed as
// one float4 {ea(h2), eb(h2), thx(f32), thy(f32)} -> 1 ds_read_b128/m-iter
// (was 3 reads: eh[m][0], eh[m][1], thr[m]).
//  Phase 1 : t<196: expvals e[t] (f32) via __cosf, inv, packed bc_s[t].
//  Phase 2 : wave w: m in [49w,49w+49). lane owns 3 patches n=lane+64k;
//            dot via 2x fdot2 (f16 in, f32 acc), edge test f32 |d| vs thx/thy,
//            accumulation f16 pk_fma; deg f16 (halves exact to 1024).
//            Tail patches 192..195: strided m + shfl_xor butterfly (f32).
//  Phase 2b: t<196 combines 4 f32 partials; self-edge w via the IDENTICAL
//            fdot2 chain on identical f16 casts -> identical w; f32 subtract.
//  Phase 3 : t<160: class j=t>>4, slice s=t&15 dots feat x W, 16-lane reduce.
//  Phase 4 : t<10 computes log_softmax, stores out[b,10].
__global__ __launch_bounds__(256, 4) void quanv_fused_kernel(
    const float* __restrict__ x,    // [B,784]
    const float* __restrict__ phi,  // [B,196,4]
    const float* __restrict__ W,    // [10,784]
    const float* __restrict__ bl,   // [10]
    float* __restrict__ out)        // [B,10]
{
    const int b    = blockIdx.x;
    const int t    = threadIdx.x;
    const int wave = t >> 6;
    const int lane = t & 63;

    __shared__ float4 e_s[NP];      // expvals (f32)
    __shared__ float  inv_s[NP];    // 1/(||e||+1e-12)
    __shared__ float4 bc_s[NP];     // {ea(h2), eb(h2), thx, thy} packed
    __shared__ float4 pa_s[4 * NP]; // per-wave partial a (f32)
    __shared__ float  pd_s[4 * NP]; // per-wave partial deg (f32)
    __shared__ float4 feat_s[NP];
    __shared__ float  logit_s[NCLS];

    const h2 H_ONE  = {(_Float16)1.0f, (_Float16)1.0f};
    const h2 H_HALF = {(_Float16)0.5f, (_Float16)0.5f};
    const h2 H_ZERO = {(_Float16)0.0f, (_Float16)0.0f};

    const float* xb = x + (size_t)b * 784;
    const float* pb = phi + (size_t)b * 784;

    // ---- Phase 1 ----
    if (t < NP) {
        const int hp = t / 14, wp = t - hp * 14;
        const int r0 = hp * 2, c0 = wp * 2;
        float th0 = xb[r0 * 28 + c0];
        float th1 = xb[r0 * 28 + c0 + 1];
        float th2 = xb[(r0 + 1) * 28 + c0];
        float th3 = xb[(r0 + 1) * 28 + c0 + 1];
        float4 ph = *(const float4*)(pb + t * 4);
        float z0 = __cosf(th0) * __cosf(ph.x);
        float z1 = __cosf(th1) * __cosf(ph.y);
        float z2 = __cosf(th2) * __cosf(ph.z);
        float z3 = __cosf(th3) * __cosf(ph.w);
        float e0 = z0;
        float e1 = e0 * z1;
        float e2 = e1 * z2;
        float e3 = e2 * z3;
        e_s[t] = make_float4(e0, e1, e2, e3);
        float nn = sqrtf(e0 * e0 + e1 * e1 + e2 * e2 + e3 * e3) + 1e-12f;
        inv_s[t] = 1.0f / nn;
        h2 ea = (h2){(_Float16)e0, (_Float16)e1};
        h2 eb = (h2){(_Float16)e2, (_Float16)e3};
        bc_s[t] = make_float4(h2_to_f(ea), h2_to_f(eb),
                              0.8944271909999159f * nn,   // sqrt(0.8)*nm
                              0.7071067811865476f * nn);  // sqrt(0.5)*nm
    }
    __syncthreads();

    // ---- Phase 2: main (all 64 lanes, 3 patches each, f16 packed body) ----
    const int m0 = wave * 49;
    {
        h2 qA[3], qB[3], aA[3], aB[3], dg[3];
        #pragma unroll
        for (int k = 0; k < 3; ++k) {
            const int n = lane + 64 * k;
            float4 q = e_s[n];
            float iv = inv_s[n];
            qA[k] = (h2){(_Float16)(q.x * iv), (_Float16)(q.y * iv)};
            qB[k] = (h2){(_Float16)(q.z * iv), (_Float16)(q.w * iv)};
            aA[k] = H_ZERO; aB[k] = H_ZERO; dg[k] = H_ZERO;
        }
        #pragma unroll 7
        for (int m = m0; m < m0 + 49; ++m) {
            float4 bc = bc_s[m];     // ONE ds_read_b128 wave-uniform broadcast
            h2 ea = f_to_h2(bc.x);
            h2 eb = f_to_h2(bc.y);
            #pragma unroll
            for (int k = 0; k < 3; ++k) {
                float d  = dot4_h(qA[k], qB[k], ea, eb);
                float ad = fabsf(d);
                h2 w2 = (ad >= bc.z) ? H_ONE : ((ad >= bc.w) ? H_HALF : H_ZERO);
                dg[k] += w2;                 // v_pk_add_f16 (halves exact)
                aA[k] += w2 * ea;            // v_pk_fma_f16
                aB[k] += w2 * eb;            // v_pk_fma_f16
            }
        }
        #pragma unroll
        for (int k = 0; k < 3; ++k) {
            pa_s[wave * NP + lane + 64 * k] =
                make_float4((float)aA[k].x, (float)aA[k].y,
                            (float)aB[k].x, (float)aB[k].y);
            pd_s[wave * NP + lane + 64 * k] = (float)dg[k].x;
        }
    }

    // ---- Phase 2 tail: patches 192..195, m-sliced across 16 lane-groups ----
    {
        const int nt    = 192 + (lane & 3);
        const int slice = lane >> 2;
        float4 q = e_s[nt];
        float iv = inv_s[nt];
        h2 qa = (h2){(_Float16)(q.x * iv), (_Float16)(q.y * iv)};
        h2 qb = (h2){(_Float16)(q.z * iv), (_Float16)(q.w * iv)};
        h2 ta = H_ZERO, tb = H_ZERO, td = H_ZERO;
        for (int m = m0 + slice; m < m0 + 49; m += 16) {
            float4 bc = bc_s[m];
            h2 ea = f_to_h2(bc.x);
            h2 eb = f_to_h2(bc.y);
            float d  = dot4_h(qa, qb, ea, eb);
            float ad = fabsf(d);
            h2 w2 = (ad >= bc.z) ? H_ONE : ((ad >= bc.w) ? H_HALF : H_ZERO);
            td += w2;
            ta += w2 * ea;
            tb += w2 * eb;
        }
        float ax = (float)ta.x, ay = (float)ta.y;
        float az = (float)tb.x, aw = (float)tb.y;
        float dt = (float)td.x;
        // butterfly over slices (offsets preserve lane&3)
        #pragma unroll
        for (int off = 4; off <= 32; off <<= 1) {
            ax += __shfl_xor(ax, off, 64);
            ay += __shfl_xor(ay, off, 64);
            az += __shfl_xor(az, off, 64);
            aw += __shfl_xor(aw, off, 64);
            dt += __shfl_xor(dt, off, 64);
        }
        if (lane < 4) {
            pa_s[wave * NP + 192 + lane] = make_float4(ax, ay, az, aw);
            pd_s[wave * NP + 192 + lane] = dt;
        }
    }
    __syncthreads();

    // ---- Phase 2b: combine partials, self-subtract, build feats ----
    if (t < NP) {
        float4 e  = e_s[t];
        float  iv = inv_s[t];
        float4 bc = bc_s[t];
        float4 at = make_float4(0.f, 0.f, 0.f, 0.f);
        float  dt = 0.f;
        #pragma unroll
        for (int w = 0; w < 4; ++w) {
            float4 p = pa_s[w * NP + t];
            at.x += p.x; at.y += p.y; at.z += p.z; at.w += p.w;
            dt += pd_s[w * NP + t];
        }
        // self-edge: IDENTICAL fdot2 chain on identical f16 casts -> same w
        h2 ea = f_to_h2(bc.x);
        h2 eb = f_to_h2(bc.y);
        h2 qa = (h2){(_Float16)(e.x * iv), (_Float16)(e.y * iv)};
        h2 qb = (h2){(_Float16)(e.z * iv), (_Float16)(e.w * iv)};
        float d  = dot4_h(qa, qb, ea, eb);
        float ad = fabsf(d);
        float w  = (ad >= bc.z) ? 1.0f : ((ad >= bc.w) ? 0.5f : 0.0f);
        dt -= w;
        at.x -= w * e.x; at.y -= w * e.y; at.z -= w * e.z; at.w -= w * e.w;
        const float s = 1.0f + dt;   // smooth = I + D - W
        feat_s[t] = make_float4(s * e.x - at.x, s * e.y - at.y,
                                s * e.z - at.z, s * e.w - at.w);
    }
    __syncthreads();

    // ---- Phase 3: logits ----
    if (t < NCLS * 16) {
        const int j  = t >> 4;
        const int sl = t & 15;
        const float4* wr = (const float4*)(W + j * 784);
        float p = 0.f;
        for (int i = sl; i < NP; i += 16) {
            float4 f  = feat_s[i];
            float4 w4 = wr[i];
            p += f.x * w4.x + f.y * w4.y + f.z * w4.z + f.w * w4.w;
        }
        #pragma unroll
        for (int off = 8; off > 0; off >>= 1)
            p += __shfl_down(p, off, 16);
        if (sl == 0) logit_s[j] = p + bl[j];
    }
    __syncthreads();

    // ---- Phase 4: log_softmax ----
    if (t < NCLS) {
        float mx = -INFINITY;
        #pragma unroll
        for (int j = 0; j < NCLS; ++j) mx = fmaxf(mx, logit_s[j]);
        float sum = 0.f;
        #pragma unroll
        for (int j = 0; j < NCLS; ++j) sum += expf(logit_s[j] - mx);
        out[(size_t)b * NCLS + t] = logit_s[t] - mx - logf(sum);
    }
}

extern "C" void kernel_launch(void* const* d_in, const int* in_sizes, int n_in,
                              void* d_out, int out_size, void* d_ws, size_t ws_size,
                              hipStream_t stream) {
    const float* x   = (const float*)d_in[0];   // [B,1,28,28]
    const float* phi = (const float*)d_in[1];   // [B,196,4]
    const float* W   = (const float*)d_in[2];   // [10,784]
    const float* bl  = (const float*)d_in[3];   // [10]
    float* out = (float*)d_out;                 // [B,10]

    const int B = in_sizes[0] / 784;
    quanv_fused_kernel<<<dim3(B), dim3(256), 0, stream>>>(x, phi, W, bl, out);
}